// Round 4
// baseline (338.690 us; speedup 1.0000x reference)
//
#include <hip/hip_runtime.h>
#include <hip/hip_bf16.h>
#include <math.h>

#define NUM_HEADS 16
#define D_KV 64
#define D_MODEL 1024
#define SEQ 2048
#define BATCH 2
#define LOG2E 1.4426950408889634f

using bf16x8 = __attribute__((ext_vector_type(8))) short;
using bf16x4 = __attribute__((ext_vector_type(4))) short;
using f32x4  = __attribute__((ext_vector_type(4))) float;

__device__ inline unsigned short f2bf(float f) {
  union { float f; unsigned int i; } v; v.f = f;
  unsigned int u = v.i;
  return (unsigned short)((u + 0x7FFFu + ((u >> 16) & 1u)) >> 16);
}
__device__ inline unsigned short f2bf_fast(float f) {
  union { float f; unsigned int i; } v; v.f = f;
  return (unsigned short)((v.i + 0x8000u) >> 16);
}

#if __has_builtin(__builtin_amdgcn_exp2f)
#define EXP2(x) __builtin_amdgcn_exp2f(x)
#else
#define EXP2(x) __expf((x) * 0.6931471805599453f)
#endif

__device__ inline unsigned int pk_bf16(float a, float b) {
#if __has_builtin(__builtin_amdgcn_cvt_pk_bf16_f32)
  auto v = __builtin_amdgcn_cvt_pk_bf16_f32(a, b);
  unsigned int u; __builtin_memcpy(&u, &v, 4);
  return u;
#else
  return ((unsigned int)f2bf_fast(b) << 16) | f2bf_fast(a);
#endif
}

// async global->LDS, 16 B per lane (dest lane-contiguous)
__device__ inline void gld_lds16(const unsigned short* g, unsigned short* l) {
  __builtin_amdgcn_global_load_lds(
      (const __attribute__((address_space(1))) unsigned int*)g,
      (__attribute__((address_space(3))) unsigned int*)l, 16, 0, 0);
}

// ---------------- fused prep: X convert + 4 weight transposes + bias table ----------------
// blocks 0..2047: X fp32->bf16 (8 elems/thread)
// blocks 2048..3071: weight transpose tiles (4 matrices x 16x16 tiles of 64x64)
// block 3072: bias table, fp32, pre-scaled by log2e: biasF[h*4096 + (rel+2047)]
__global__ __launch_bounds__(256) void prep_kernel(const float* __restrict__ X,
                                                   const float* __restrict__ W0,
                                                   const float* __restrict__ W1,
                                                   const float* __restrict__ W2,
                                                   const float* __restrict__ W3,
                                                   const float* __restrict__ tbl,
                                                   unsigned short* __restrict__ xbf,
                                                   unsigned short* __restrict__ wt,
                                                   float* __restrict__ biasF) {
  __shared__ __align__(16) unsigned short T[64][72];
  int bid = blockIdx.x;
  int t = threadIdx.x;
  if (bid < 2048) {
    int i = (bid * 256 + t) * 8;
    __align__(16) unsigned short tmp[8];
#pragma unroll
    for (int e = 0; e < 8; e++) tmp[e] = f2bf(X[i + e]);
    *(uint4*)&xbf[i] = *(uint4*)tmp;
  } else if (bid < 3072) {
    int rem = bid - 2048;
    int z = rem >> 8, tid = rem & 255;
    const float* in = (z == 0) ? W0 : (z == 1) ? W1 : (z == 2) ? W2 : W3;
    unsigned short* o = wt + (long)z * 1048576;
    int r0 = (tid & 15) * 64, c0 = (tid >> 4) * 64;
#pragma unroll
    for (int i = 0; i < 2; i++) {
      int c = t + 256 * i; int r = c >> 3, k8 = (c & 7) * 8;
      const float* src = &in[(long)(r0 + r) * 1024 + c0 + k8];
      __align__(16) unsigned short tmp[8];
#pragma unroll
      for (int e = 0; e < 8; e++) tmp[e] = f2bf(src[e]);
      *(uint4*)&T[r][k8] = *(uint4*)tmp;
    }
    __syncthreads();
#pragma unroll
    for (int i = 0; i < 2; i++) {
      int c = t + 256 * i; int r = c >> 3, k8 = (c & 7) * 8;
      __align__(16) unsigned short tmp[8];
#pragma unroll
      for (int e = 0; e < 8; e++) tmp[e] = T[k8 + e][r];
      *(uint4*)&o[(long)(c0 + r) * 1024 + r0 + k8] = *(uint4*)tmp;
    }
  } else {
#pragma unroll
    for (int ii = 0; ii < 16; ii++) {
      int idx = t + 256 * ii;
      if (idx >= 4095) break;
      int rel = idx - 2047;
      int bucket = (rel > 0) ? 16 : 0;
      int rp = rel < 0 ? -rel : rel;
      int add;
      if (rp < 8) add = rp;
      else {
        int rl = 8 + (int)(logf((float)rp * 0.125f) / logf(16.0f) * 8.0f);
        add = rl < 15 ? rl : 15;
      }
      bucket += add;
#pragma unroll
      for (int h = 0; h < 16; h++) biasF[h * 4096 + idx] = tbl[bucket * 16 + h] * LOG2E;
    }
  }
}

// ---------------- bf16 (RxC) -> bf16 (CxR) transpose, batched ----------------
__global__ __launch_bounds__(256) void transpose_b2b(const unsigned short* __restrict__ in,
                                                     unsigned short* __restrict__ out,
                                                     int in_stride, int out_stride,
                                                     long in_bstride, long out_bstride) {
  __shared__ __align__(16) unsigned short T[64][72];
  in  += blockIdx.z * in_bstride;
  out += blockIdx.z * out_bstride;
  int r0 = blockIdx.x * 64, c0 = blockIdx.y * 64;
  int t = threadIdx.x;
#pragma unroll
  for (int i = 0; i < 2; i++) {
    int c = t + 256 * i; int r = c >> 3, k8 = (c & 7) * 8;
    *(uint4*)&T[r][k8] = *(const uint4*)&in[(long)(r0 + r) * in_stride + c0 + k8];
  }
  __syncthreads();
#pragma unroll
  for (int i = 0; i < 2; i++) {
    int c = t + 256 * i; int r = c >> 3, k8 = (c & 7) * 8;
    __align__(16) unsigned short tmp[8];
#pragma unroll
    for (int e = 0; e < 8; e++) tmp[e] = T[k8 + e][r];
    *(uint4*)&out[(long)(c0 + r) * out_stride + r0 + k8] = *(uint4*)tmp;
  }
}

// ---------------- GEMM: C(MxN) = X(MxK) @ Wt(NxK)^T, K=1024, global_load_lds staging ----------------
// mode 0: bf16 epilogue scattered to (B,H,S,D); z==0 (Q) scaled by log2e
// mode 1: fp32 row-major epilogue
__global__ __launch_bounds__(256) void gemm_kernel(const unsigned short* __restrict__ X,
                                                   const unsigned short* __restrict__ Wt,
                                                   unsigned short* __restrict__ out_b,
                                                   float* __restrict__ out_f, int mode) {
  __shared__ __align__(16) unsigned short As[128 * 32];
  __shared__ __align__(16) unsigned short Bs[128 * 32];
  const int K = 1024;
  int m0 = blockIdx.x * 128;
  int n0 = blockIdx.y * 128;
  const unsigned short* W = Wt + (long)blockIdx.z * 1048576;
  unsigned short* outq = (mode == 0) ? out_b + (long)blockIdx.z * 4194304 : nullptr;
  float scale = (mode == 0 && blockIdx.z == 0) ? LOG2E : 1.0f;
  int t = threadIdx.x;
  int w = t >> 6, l = t & 63;
  int wr = (w >> 1) * 64, wc = (w & 1) * 64;
  int lr = l & 15, lq = l >> 4;
  f32x4 acc[4][4];
#pragma unroll
  for (int i = 0; i < 4; i++)
#pragma unroll
    for (int j = 0; j < 4; j++) acc[i][j] = (f32x4){0.f, 0.f, 0.f, 0.f};

  for (int k0 = 0; k0 < K; k0 += 32) {
#pragma unroll
    for (int i = 0; i < 2; i++) {
      int c = t + 256 * i;
      int r = c >> 2, kc = (c & 3) * 8;
      gld_lds16(&X[(long)(m0 + r) * K + k0 + kc], &As[c * 8]);
      gld_lds16(&W[(long)(n0 + r) * K + k0 + kc], &Bs[c * 8]);
    }
    __syncthreads();
    bf16x8 a[4], b[4];
#pragma unroll
    for (int mi = 0; mi < 4; mi++) a[mi] = *(const bf16x8*)&As[(wr + mi * 16 + lr) * 32 + lq * 8];
#pragma unroll
    for (int ni = 0; ni < 4; ni++) b[ni] = *(const bf16x8*)&Bs[(wc + ni * 16 + lr) * 32 + lq * 8];
#pragma unroll
    for (int mi = 0; mi < 4; mi++)
#pragma unroll
      for (int ni = 0; ni < 4; ni++)
        acc[mi][ni] = __builtin_amdgcn_mfma_f32_16x16x32_bf16(a[mi], b[ni], acc[mi][ni], 0, 0, 0);
    __syncthreads();
  }
#pragma unroll
  for (int mi = 0; mi < 4; mi++)
#pragma unroll
    for (int ni = 0; ni < 4; ni++)
#pragma unroll
      for (int r = 0; r < 4; r++) {
        int m = m0 + wr + mi * 16 + lq * 4 + r;
        int n = n0 + wc + ni * 16 + lr;
        float vf = acc[mi][ni][r] * scale;
        if (mode == 0) {
          int b_ = m >> 11, s = m & 2047, h = n >> 6, d = n & 63;
          outq[(((long)(b_ * NUM_HEADS + h) * SEQ) + s) * 64 + d] = f2bf(vf);
        } else {
          out_f[(long)m * 1024 + n] = vf;
        }
      }
}

// ---------------- flash attention, transposed scores (S^T = K Q^T), exp2 softmax ----------------
// Q (pre-scaled by log2e), K: (B*H,S,64) bf16; Vt: (B*H,64,S) bf16; O: (B,S,H*64) bf16
// biasF: fp32, pre-scaled by log2e, [h][rel+2047] stride 4096.
// Single-buffered K/V LDS (reg prefetch, 2 barriers/iter); bias: 2 shift-replicated fp32
// LDS copies -> aligned float2 reads (conflict-free); P stays in registers (16x16x16bf16_1k).
__global__ __launch_bounds__(256, 4) void attn_kernel(const unsigned short* __restrict__ Q,
                                                      const unsigned short* __restrict__ Km,
                                                      const unsigned short* __restrict__ Vt,
                                                      const float* __restrict__ biasF,
                                                      unsigned short* __restrict__ O) {
  __shared__ __align__(16) unsigned short Ks[64 * 72];
  __shared__ __align__(16) unsigned short Vs[64 * 72];
  __shared__ __align__(16) float biasRf[2][2176];
  int q0 = blockIdx.x * 128;
  int bh = blockIdx.y;
  int b_ = bh >> 4, h = bh & 15;
  const unsigned short* Qb = Q  + (long)bh * SEQ * 64;
  const unsigned short* Kb = Km + (long)bh * SEQ * 64;
  const unsigned short* Vb = Vt + (long)bh * 64 * SEQ;
  const float* btabF = biasF + h * 4096;
  int t = threadIdx.x;
  int w = t >> 6, l = t & 63;
  int lr = l & 15, lq = l >> 4;
  int qw = w * 32;

  // stage 2 shift-replicated fp32 bias copies: biasRf[j][i] = btabF[gbase + i + j]
  int gbase = 1920 - q0;
  for (int i = t; i < 2176; i += 256) {
    int g0 = gbase + i;     if (g0 > 4094) g0 = 4094;
    int g1 = gbase + i + 1; if (g1 > 4094) g1 = 4094;
    biasRf[0][i] = btabF[g0];
    biasRf[1][i] = btabF[g1];
  }

  // Q fragments (B-operand for S^T), registers for whole kernel
  bf16x8 aq[2][2];
#pragma unroll
  for (int qt = 0; qt < 2; qt++)
#pragma unroll
    for (int ks = 0; ks < 2; ks++)
      aq[qt][ks] = *(const bf16x8*)&Qb[(long)(q0 + qw + qt * 16 + lr) * 64 + ks * 32 + lq * 8];

  // staging chunk coords
  int c0 = t, c1 = t + 256;
  int r0s = c0 >> 3, f0 = (c0 & 7) * 8;
  int r1s = c1 >> 3, f1 = (c1 & 7) * 8;

  // prologue: tile 0 regs -> LDS
  uint4 kca = *(const uint4*)&Kb[(long)r0s * 64 + f0];
  uint4 kcb = *(const uint4*)&Kb[(long)r1s * 64 + f1];
  uint4 vca = *(const uint4*)&Vb[(long)r0s * SEQ + f0];
  uint4 vcb = *(const uint4*)&Vb[(long)r1s * SEQ + f1];
  *(uint4*)&Ks[r0s * 72 + f0] = kca;
  *(uint4*)&Ks[r1s * 72 + f1] = kcb;
  *(uint4*)&Vs[r0s * 72 + f0] = vca;
  *(uint4*)&Vs[r1s * 72 + f1] = vcb;

  f32x4 accO[4][2];   // [dt][qt], O^T C-tiles (row=d, col=q)
  f32x4 accL[2];
#pragma unroll
  for (int qt = 0; qt < 2; qt++) {
    accL[qt] = (f32x4){0.f, 0.f, 0.f, 0.f};
#pragma unroll
    for (int dt = 0; dt < 4; dt++) accO[dt][qt] = (f32x4){0.f, 0.f, 0.f, 0.f};
  }

  bf16x4 ones4;
#pragma unroll
  for (int e = 0; e < 4; e++) ones4[e] = (short)0x3F80;

  // bias index: global idx = vb + k0 + kt*16 - qt*16 + r
  int vb = 127 + lq * 4 - qw - lr;
  int bj2 = vb & 1;                    // shift-row selector; vb - bj2 is even
  const float* brow = biasRf[bj2];
  int pbc = vb - bj2 - 16;             // + k0 + 16m at read time (m = kt-qt+1)

  for (int k0 = 0; k0 < SEQ; k0 += 64) {
    __syncthreads();   // tile visible
    bool more = (k0 + 64) < SEQ;

    // ---- bias blocks for this iter (5 x 2 float2, conflict-free) ----
    float2 bbl[5][2];
    int pb = pbc + k0;
#pragma unroll
    for (int m = 0; m < 5; m++) {
      bbl[m][0] = *(const float2*)&brow[pb + 16 * m];
      bbl[m][1] = *(const float2*)&brow[pb + 16 * m + 2];
    }

    // ---- K fragments ----
    bf16x8 bk[4][2];
#pragma unroll
    for (int kt = 0; kt < 4; kt++)
#pragma unroll
      for (int ks = 0; ks < 2; ks++)
        bk[kt][ks] = *(const bf16x8*)&Ks[(kt * 16 + lr) * 72 + ks * 32 + lq * 8];

    // ---- prefetch next tile -> regs (lands during compute) ----
    if (more) {
      const unsigned short* Kn = Kb + (long)(k0 + 64) * 64;
      const unsigned short* Vn = Vb + (k0 + 64);
      kca = *(const uint4*)&Kn[(long)r0s * 64 + f0];
      kcb = *(const uint4*)&Kn[(long)r1s * 64 + f1];
      vca = *(const uint4*)&Vn[(long)r0s * SEQ + f0];
      vcb = *(const uint4*)&Vn[(long)r1s * SEQ + f1];
    }

    // ---- S^T = K Q^T ----
    f32x4 sacc[4][2];
#pragma unroll
    for (int kt = 0; kt < 4; kt++)
#pragma unroll
      for (int qt = 0; qt < 2; qt++) sacc[kt][qt] = (f32x4){0.f, 0.f, 0.f, 0.f};
#pragma unroll
    for (int ks = 0; ks < 2; ks++)
#pragma unroll
      for (int kt = 0; kt < 4; kt++)
#pragma unroll
        for (int qt = 0; qt < 2; qt++)
          sacc[kt][qt] = __builtin_amdgcn_mfma_f32_16x16x32_bf16(bk[kt][ks], aq[qt][ks], sacc[kt][qt], 0, 0, 0);

    // ---- p = exp2(s + bias'), pack to bf16 in regs (P^T C-layout) ----
    bf16x4 pk[4][2];
#pragma unroll
    for (int kt = 0; kt < 4; kt++)
#pragma unroll
      for (int qt = 0; qt < 2; qt++) {
        int blk = kt - qt + 1;
        float p0 = EXP2(sacc[kt][qt][0] + bbl[blk][0].x);
        float p1 = EXP2(sacc[kt][qt][1] + bbl[blk][0].y);
        float p2 = EXP2(sacc[kt][qt][2] + bbl[blk][1].x);
        float p3 = EXP2(sacc[kt][qt][3] + bbl[blk][1].y);
        unsigned int uu[2] = { pk_bf16(p0, p1), pk_bf16(p2, p3) };
        bf16x4 pv; __builtin_memcpy(&pv, uu, 8);
        pk[kt][qt] = pv;
      }

    // ---- O^T += V^T P^T ; row sums via ones ----
#pragma unroll
    for (int kt = 0; kt < 4; kt++) {
      bf16x4 va[4];
#pragma unroll
      for (int dt = 0; dt < 4; dt++)
        va[dt] = *(const bf16x4*)&Vs[(dt * 16 + lr) * 72 + kt * 16 + lq * 4];
#pragma unroll
      for (int qt = 0; qt < 2; qt++) {
#pragma unroll
        for (int dt = 0; dt < 4; dt++)
          accO[dt][qt] = __builtin_amdgcn_mfma_f32_16x16x16bf16_1k(va[dt], pk[kt][qt], accO[dt][qt], 0, 0, 0);
        accL[qt] = __builtin_amdgcn_mfma_f32_16x16x16bf16_1k(ones4, pk[kt][qt], accL[qt], 0, 0, 0);
      }
    }

    __syncthreads();   // all reads of current tile done
    if (more) {
      *(uint4*)&Ks[r0s * 72 + f0] = kca;
      *(uint4*)&Ks[r1s * 72 + f1] = kcb;
      *(uint4*)&Vs[r0s * 72 + f0] = vca;
      *(uint4*)&Vs[r1s * 72 + f1] = vcb;
    }
  }

  // ---- epilogue: normalize, pack 4 consecutive d, store 8 B per (dt,qt) ----
#pragma unroll
  for (int qt = 0; qt < 2; qt++) {
    float rl = 1.0f / accL[qt][0];
    int q = q0 + qw + qt * 16 + lr;
#pragma unroll
    for (int dt = 0; dt < 4; dt++) {
      unsigned int s0 = ((unsigned int)f2bf(accO[dt][qt][1] * rl) << 16) | f2bf(accO[dt][qt][0] * rl);
      unsigned int s1 = ((unsigned int)f2bf(accO[dt][qt][3] * rl) << 16) | f2bf(accO[dt][qt][2] * rl);
      *(uint2*)&O[((long)(b_ * SEQ + q)) * 1024 + h * 64 + dt * 16 + lq * 4] = (uint2){s0, s1};
    }
  }
}

extern "C" void kernel_launch(void* const* d_in, const int* in_sizes, int n_in,
                              void* d_out, int out_size, void* d_ws, size_t ws_size,
                              hipStream_t stream) {
  const float* X   = (const float*)d_in[0];
  const float* Wq  = (const float*)d_in[1];
  const float* Wk  = (const float*)d_in[2];
  const float* Wv  = (const float*)d_in[3];
  const float* Wo  = (const float*)d_in[4];
  const float* tbl = (const float*)d_in[5];

  unsigned short* wt    = (unsigned short*)d_ws;       // 4 x 1M elems (Wq,Wk,Wv,Wo transposed)
  unsigned short* xbf   = wt + 4 * 1048576;            // 4M elems
  unsigned short* q_ws  = xbf + 4194304;               // Q,K,V contiguous (4M each)
  unsigned short* k_ws  = q_ws + 4194304;
  unsigned short* v_ws  = k_ws + 4194304;
  unsigned short* vt_ws = v_ws + 4194304;
  unsigned short* o_ws  = vt_ws + 4194304;
  float* biasF = (float*)(o_ws + 4194304);             // 16 x 4096 fp32 (log2e-scaled)

  prep_kernel<<<3073, 256, 0, stream>>>(X, Wq, Wk, Wv, Wo, tbl, xbf, wt, biasF);
  gemm_kernel<<<dim3(32, 8, 3), 256, 0, stream>>>(xbf, wt, q_ws, nullptr, 0);
  transpose_b2b<<<dim3(32, 1, 32), 256, 0, stream>>>(v_ws, vt_ws, 64, 2048, 131072L, 131072L);
  attn_kernel<<<dim3(16, 32), 256, 0, stream>>>(q_ws, k_ws, vt_ws, biasF, o_ws);
  gemm_kernel<<<dim3(32, 8, 1), 256, 0, stream>>>(o_ws, wt + 3 * 1048576, nullptr, (float*)d_out, 1);
}

// Round 5
// 216.055 us; speedup vs baseline: 1.5676x; 1.5676x over previous
//
#include <hip/hip_runtime.h>
#include <hip/hip_bf16.h>
#include <math.h>

#define NUM_HEADS 16
#define D_KV 64
#define D_MODEL 1024
#define SEQ 2048
#define BATCH 2
#define LOG2E 1.4426950408889634f

using bf16x8 = __attribute__((ext_vector_type(8))) short;
using bf16x4 = __attribute__((ext_vector_type(4))) short;
using f32x4  = __attribute__((ext_vector_type(4))) float;

__device__ inline unsigned short f2bf(float f) {
  union { float f; unsigned int i; } v; v.f = f;
  unsigned int u = v.i;
  return (unsigned short)((u + 0x7FFFu + ((u >> 16) & 1u)) >> 16);
}
__device__ inline unsigned short f2bf_fast(float f) {
  union { float f; unsigned int i; } v; v.f = f;
  return (unsigned short)((v.i + 0x8000u) >> 16);
}

#if __has_builtin(__builtin_amdgcn_exp2f)
#define EXP2(x) __builtin_amdgcn_exp2f(x)
#else
#define EXP2(x) __expf((x) * 0.6931471805599453f)
#endif

__device__ inline unsigned int pk_bf16(float a, float b) {
#if __has_builtin(__builtin_amdgcn_cvt_pk_bf16_f32)
  auto v = __builtin_amdgcn_cvt_pk_bf16_f32(a, b);
  unsigned int u; __builtin_memcpy(&u, &v, 4);
  return u;
#else
  return ((unsigned int)f2bf_fast(b) << 16) | f2bf_fast(a);
#endif
}

// async global->LDS, 16 B per lane (dest lane-contiguous)
__device__ inline void gld_lds16(const unsigned short* g, unsigned short* l) {
  __builtin_amdgcn_global_load_lds(
      (const __attribute__((address_space(1))) unsigned int*)g,
      (__attribute__((address_space(3))) unsigned int*)l, 16, 0, 0);
}

// ---------------- fused prep: X convert + 4 weight transposes + bias table ----------------
__global__ __launch_bounds__(256) void prep_kernel(const float* __restrict__ X,
                                                   const float* __restrict__ W0,
                                                   const float* __restrict__ W1,
                                                   const float* __restrict__ W2,
                                                   const float* __restrict__ W3,
                                                   const float* __restrict__ tbl,
                                                   unsigned short* __restrict__ xbf,
                                                   unsigned short* __restrict__ wt,
                                                   float* __restrict__ biasF) {
  __shared__ __align__(16) unsigned short T[64][72];
  int bid = blockIdx.x;
  int t = threadIdx.x;
  if (bid < 2048) {
    int i = (bid * 256 + t) * 8;
    __align__(16) unsigned short tmp[8];
#pragma unroll
    for (int e = 0; e < 8; e++) tmp[e] = f2bf(X[i + e]);
    *(uint4*)&xbf[i] = *(uint4*)tmp;
  } else if (bid < 3072) {
    int rem = bid - 2048;
    int z = rem >> 8, tid = rem & 255;
    const float* in = (z == 0) ? W0 : (z == 1) ? W1 : (z == 2) ? W2 : W3;
    unsigned short* o = wt + (long)z * 1048576;
    int r0 = (tid & 15) * 64, c0 = (tid >> 4) * 64;
#pragma unroll
    for (int i = 0; i < 2; i++) {
      int c = t + 256 * i; int r = c >> 3, k8 = (c & 7) * 8;
      const float* src = &in[(long)(r0 + r) * 1024 + c0 + k8];
      __align__(16) unsigned short tmp[8];
#pragma unroll
      for (int e = 0; e < 8; e++) tmp[e] = f2bf(src[e]);
      *(uint4*)&T[r][k8] = *(uint4*)tmp;
    }
    __syncthreads();
#pragma unroll
    for (int i = 0; i < 2; i++) {
      int c = t + 256 * i; int r = c >> 3, k8 = (c & 7) * 8;
      __align__(16) unsigned short tmp[8];
#pragma unroll
      for (int e = 0; e < 8; e++) tmp[e] = T[k8 + e][r];
      *(uint4*)&o[(long)(c0 + r) * 1024 + r0 + k8] = *(uint4*)tmp;
    }
  } else {
#pragma unroll
    for (int ii = 0; ii < 16; ii++) {
      int idx = t + 256 * ii;
      if (idx >= 4095) break;
      int rel = idx - 2047;
      int bucket = (rel > 0) ? 16 : 0;
      int rp = rel < 0 ? -rel : rel;
      int add;
      if (rp < 8) add = rp;
      else {
        int rl = 8 + (int)(logf((float)rp * 0.125f) / logf(16.0f) * 8.0f);
        add = rl < 15 ? rl : 15;
      }
      bucket += add;
#pragma unroll
      for (int h = 0; h < 16; h++) biasF[h * 4096 + idx] = tbl[bucket * 16 + h] * LOG2E;
    }
  }
}

// ---------------- bf16 (RxC) -> bf16 (CxR) transpose, batched ----------------
__global__ __launch_bounds__(256) void transpose_b2b(const unsigned short* __restrict__ in,
                                                     unsigned short* __restrict__ out,
                                                     int in_stride, int out_stride,
                                                     long in_bstride, long out_bstride) {
  __shared__ __align__(16) unsigned short T[64][72];
  in  += blockIdx.z * in_bstride;
  out += blockIdx.z * out_bstride;
  int r0 = blockIdx.x * 64, c0 = blockIdx.y * 64;
  int t = threadIdx.x;
#pragma unroll
  for (int i = 0; i < 2; i++) {
    int c = t + 256 * i; int r = c >> 3, k8 = (c & 7) * 8;
    *(uint4*)&T[r][k8] = *(const uint4*)&in[(long)(r0 + r) * in_stride + c0 + k8];
  }
  __syncthreads();
#pragma unroll
  for (int i = 0; i < 2; i++) {
    int c = t + 256 * i; int r = c >> 3, k8 = (c & 7) * 8;
    __align__(16) unsigned short tmp[8];
#pragma unroll
    for (int e = 0; e < 8; e++) tmp[e] = T[k8 + e][r];
    *(uint4*)&out[(long)(c0 + r) * out_stride + r0 + k8] = *(uint4*)tmp;
  }
}

// ---------------- GEMM: C(MxN) = X(MxK) @ Wt(NxK)^T, K=1024, global_load_lds staging ----------------
__global__ __launch_bounds__(256) void gemm_kernel(const unsigned short* __restrict__ X,
                                                   const unsigned short* __restrict__ Wt,
                                                   unsigned short* __restrict__ out_b,
                                                   float* __restrict__ out_f, int mode) {
  __shared__ __align__(16) unsigned short As[128 * 32];
  __shared__ __align__(16) unsigned short Bs[128 * 32];
  const int K = 1024;
  int m0 = blockIdx.x * 128;
  int n0 = blockIdx.y * 128;
  const unsigned short* W = Wt + (long)blockIdx.z * 1048576;
  unsigned short* outq = (mode == 0) ? out_b + (long)blockIdx.z * 4194304 : nullptr;
  float scale = (mode == 0 && blockIdx.z == 0) ? LOG2E : 1.0f;
  int t = threadIdx.x;
  int w = t >> 6, l = t & 63;
  int wr = (w >> 1) * 64, wc = (w & 1) * 64;
  int lr = l & 15, lq = l >> 4;
  f32x4 acc[4][4];
#pragma unroll
  for (int i = 0; i < 4; i++)
#pragma unroll
    for (int j = 0; j < 4; j++) acc[i][j] = (f32x4){0.f, 0.f, 0.f, 0.f};

  for (int k0 = 0; k0 < K; k0 += 32) {
#pragma unroll
    for (int i = 0; i < 2; i++) {
      int c = t + 256 * i;
      int r = c >> 2, kc = (c & 3) * 8;
      gld_lds16(&X[(long)(m0 + r) * K + k0 + kc], &As[c * 8]);
      gld_lds16(&W[(long)(n0 + r) * K + k0 + kc], &Bs[c * 8]);
    }
    __syncthreads();
    bf16x8 a[4], b[4];
#pragma unroll
    for (int mi = 0; mi < 4; mi++) a[mi] = *(const bf16x8*)&As[(wr + mi * 16 + lr) * 32 + lq * 8];
#pragma unroll
    for (int ni = 0; ni < 4; ni++) b[ni] = *(const bf16x8*)&Bs[(wc + ni * 16 + lr) * 32 + lq * 8];
#pragma unroll
    for (int mi = 0; mi < 4; mi++)
#pragma unroll
      for (int ni = 0; ni < 4; ni++)
        acc[mi][ni] = __builtin_amdgcn_mfma_f32_16x16x32_bf16(a[mi], b[ni], acc[mi][ni], 0, 0, 0);
    __syncthreads();
  }
#pragma unroll
  for (int mi = 0; mi < 4; mi++)
#pragma unroll
    for (int ni = 0; ni < 4; ni++)
#pragma unroll
      for (int r = 0; r < 4; r++) {
        int m = m0 + wr + mi * 16 + lq * 4 + r;
        int n = n0 + wc + ni * 16 + lr;
        float vf = acc[mi][ni][r] * scale;
        if (mode == 0) {
          int b_ = m >> 11, s = m & 2047, h = n >> 6, d = n & 63;
          outq[(((long)(b_ * NUM_HEADS + h) * SEQ) + s) * 64 + d] = f2bf(vf);
        } else {
          out_f[(long)m * 1024 + n] = vf;
        }
      }
}

// ---------------- flash attention, transposed scores (S^T = K Q^T), exp2 softmax ----------------
// Q (pre-scaled by log2e), K: (B*H,S,64) bf16; Vt: (B*H,64,S) bf16; O: (B,S,H*64) bf16
// biasF: fp32, pre-scaled by log2e, [h][rel+2047] stride 4096.
// Single-buffered K/V LDS (reg prefetch, 2 barriers/iter); bias: 2 shift-replicated fp32
// LDS copies -> aligned float2 reads; P stays in registers (16x16x16bf16_1k).
// NOTE: min-waves bound must stay at 2 — (256,4) forces a 128-VGPR cap and the
// ~170-VGPR loop state spills to scratch (R4: WRITE_SIZE 8 MB -> 417 MB, 3x slower).
__global__ __launch_bounds__(256, 2) void attn_kernel(const unsigned short* __restrict__ Q,
                                                      const unsigned short* __restrict__ Km,
                                                      const unsigned short* __restrict__ Vt,
                                                      const float* __restrict__ biasF,
                                                      unsigned short* __restrict__ O) {
  __shared__ __align__(16) unsigned short Ks[64 * 72];
  __shared__ __align__(16) unsigned short Vs[64 * 72];
  __shared__ __align__(16) float biasRf[2][2176];
  int q0 = blockIdx.x * 128;
  int bh = blockIdx.y;
  int b_ = bh >> 4, h = bh & 15;
  const unsigned short* Qb = Q  + (long)bh * SEQ * 64;
  const unsigned short* Kb = Km + (long)bh * SEQ * 64;
  const unsigned short* Vb = Vt + (long)bh * 64 * SEQ;
  const float* btabF = biasF + h * 4096;
  int t = threadIdx.x;
  int w = t >> 6, l = t & 63;
  int lr = l & 15, lq = l >> 4;
  int qw = w * 32;

  // stage 2 shift-replicated fp32 bias copies
  int gbase = 1920 - q0;
  for (int i = t; i < 2176; i += 256) {
    int g0 = gbase + i;     if (g0 > 4094) g0 = 4094;
    int g1 = gbase + i + 1; if (g1 > 4094) g1 = 4094;
    biasRf[0][i] = btabF[g0];
    biasRf[1][i] = btabF[g1];
  }

  // Q fragments (B-operand for S^T), registers for whole kernel
  bf16x8 aq[2][2];
#pragma unroll
  for (int qt = 0; qt < 2; qt++)
#pragma unroll
    for (int ks = 0; ks < 2; ks++)
      aq[qt][ks] = *(const bf16x8*)&Qb[(long)(q0 + qw + qt * 16 + lr) * 64 + ks * 32 + lq * 8];

  // staging chunk coords
  int c0 = t, c1 = t + 256;
  int r0s = c0 >> 3, f0 = (c0 & 7) * 8;
  int r1s = c1 >> 3, f1 = (c1 & 7) * 8;

  // prologue: tile 0 regs -> LDS
  uint4 kca = *(const uint4*)&Kb[(long)r0s * 64 + f0];
  uint4 kcb = *(const uint4*)&Kb[(long)r1s * 64 + f1];
  uint4 vca = *(const uint4*)&Vb[(long)r0s * SEQ + f0];
  uint4 vcb = *(const uint4*)&Vb[(long)r1s * SEQ + f1];
  *(uint4*)&Ks[r0s * 72 + f0] = kca;
  *(uint4*)&Ks[r1s * 72 + f1] = kcb;
  *(uint4*)&Vs[r0s * 72 + f0] = vca;
  *(uint4*)&Vs[r1s * 72 + f1] = vcb;

  f32x4 accO[4][2];   // [dt][qt], O^T C-tiles (row=d, col=q)
  f32x4 accL[2];
#pragma unroll
  for (int qt = 0; qt < 2; qt++) {
    accL[qt] = (f32x4){0.f, 0.f, 0.f, 0.f};
#pragma unroll
    for (int dt = 0; dt < 4; dt++) accO[dt][qt] = (f32x4){0.f, 0.f, 0.f, 0.f};
  }

  bf16x4 ones4;
#pragma unroll
  for (int e = 0; e < 4; e++) ones4[e] = (short)0x3F80;

  // bias index: global idx = vb + k0 + kt*16 - qt*16 + r
  int vb = 127 + lq * 4 - qw - lr;
  int bj2 = vb & 1;
  const float* brow = biasRf[bj2];
  int pbc = vb - bj2 - 16;

  for (int k0 = 0; k0 < SEQ; k0 += 64) {
    __syncthreads();   // tile visible
    bool more = (k0 + 64) < SEQ;

    // ---- bias blocks for this iter (5 x 2 float2, conflict-free) ----
    float2 bbl[5][2];
    int pb = pbc + k0;
#pragma unroll
    for (int m = 0; m < 5; m++) {
      bbl[m][0] = *(const float2*)&brow[pb + 16 * m];
      bbl[m][1] = *(const float2*)&brow[pb + 16 * m + 2];
    }

    // ---- K fragments ----
    bf16x8 bk[4][2];
#pragma unroll
    for (int kt = 0; kt < 4; kt++)
#pragma unroll
      for (int ks = 0; ks < 2; ks++)
        bk[kt][ks] = *(const bf16x8*)&Ks[(kt * 16 + lr) * 72 + ks * 32 + lq * 8];

    // ---- prefetch next tile -> regs (lands during compute) ----
    if (more) {
      const unsigned short* Kn = Kb + (long)(k0 + 64) * 64;
      const unsigned short* Vn = Vb + (k0 + 64);
      kca = *(const uint4*)&Kn[(long)r0s * 64 + f0];
      kcb = *(const uint4*)&Kn[(long)r1s * 64 + f1];
      vca = *(const uint4*)&Vn[(long)r0s * SEQ + f0];
      vcb = *(const uint4*)&Vn[(long)r1s * SEQ + f1];
    }

    // ---- S^T = K Q^T ----
    f32x4 sacc[4][2];
#pragma unroll
    for (int kt = 0; kt < 4; kt++)
#pragma unroll
      for (int qt = 0; qt < 2; qt++) sacc[kt][qt] = (f32x4){0.f, 0.f, 0.f, 0.f};
#pragma unroll
    for (int ks = 0; ks < 2; ks++)
#pragma unroll
      for (int kt = 0; kt < 4; kt++)
#pragma unroll
        for (int qt = 0; qt < 2; qt++)
          sacc[kt][qt] = __builtin_amdgcn_mfma_f32_16x16x32_bf16(bk[kt][ks], aq[qt][ks], sacc[kt][qt], 0, 0, 0);

    // ---- p = exp2(s + bias'), pack to bf16 in regs (P^T C-layout) ----
    bf16x4 pk[4][2];
#pragma unroll
    for (int kt = 0; kt < 4; kt++)
#pragma unroll
      for (int qt = 0; qt < 2; qt++) {
        int blk = kt - qt + 1;
        float p0 = EXP2(sacc[kt][qt][0] + bbl[blk][0].x);
        float p1 = EXP2(sacc[kt][qt][1] + bbl[blk][0].y);
        float p2 = EXP2(sacc[kt][qt][2] + bbl[blk][1].x);
        float p3 = EXP2(sacc[kt][qt][3] + bbl[blk][1].y);
        unsigned int uu[2] = { pk_bf16(p0, p1), pk_bf16(p2, p3) };
        bf16x4 pv; __builtin_memcpy(&pv, uu, 8);
        pk[kt][qt] = pv;
      }

    // ---- O^T += V^T P^T ; row sums via ones ----
#pragma unroll
    for (int kt = 0; kt < 4; kt++) {
      bf16x4 va[4];
#pragma unroll
      for (int dt = 0; dt < 4; dt++)
        va[dt] = *(const bf16x4*)&Vs[(dt * 16 + lr) * 72 + kt * 16 + lq * 4];
#pragma unroll
      for (int qt = 0; qt < 2; qt++) {
#pragma unroll
        for (int dt = 0; dt < 4; dt++)
          accO[dt][qt] = __builtin_amdgcn_mfma_f32_16x16x16bf16_1k(va[dt], pk[kt][qt], accO[dt][qt], 0, 0, 0);
        accL[qt] = __builtin_amdgcn_mfma_f32_16x16x16bf16_1k(ones4, pk[kt][qt], accL[qt], 0, 0, 0);
      }
    }

    __syncthreads();   // all reads of current tile done
    if (more) {
      *(uint4*)&Ks[r0s * 72 + f0] = kca;
      *(uint4*)&Ks[r1s * 72 + f1] = kcb;
      *(uint4*)&Vs[r0s * 72 + f0] = vca;
      *(uint4*)&Vs[r1s * 72 + f1] = vcb;
    }
  }

  // ---- epilogue: normalize, pack 4 consecutive d, store 8 B per (dt,qt) ----
#pragma unroll
  for (int qt = 0; qt < 2; qt++) {
    float rl = 1.0f / accL[qt][0];
    int q = q0 + qw + qt * 16 + lr;
#pragma unroll
    for (int dt = 0; dt < 4; dt++) {
      unsigned int s0 = ((unsigned int)f2bf(accO[dt][qt][1] * rl) << 16) | f2bf(accO[dt][qt][0] * rl);
      unsigned int s1 = ((unsigned int)f2bf(accO[dt][qt][3] * rl) << 16) | f2bf(accO[dt][qt][2] * rl);
      *(uint2*)&O[((long)(b_ * SEQ + q)) * 1024 + h * 64 + dt * 16 + lq * 4] = (uint2){s0, s1};
    }
  }
}

extern "C" void kernel_launch(void* const* d_in, const int* in_sizes, int n_in,
                              void* d_out, int out_size, void* d_ws, size_t ws_size,
                              hipStream_t stream) {
  const float* X   = (const float*)d_in[0];
  const float* Wq  = (const float*)d_in[1];
  const float* Wk  = (const float*)d_in[2];
  const float* Wv  = (const float*)d_in[3];
  const float* Wo  = (const float*)d_in[4];
  const float* tbl = (const float*)d_in[5];

  unsigned short* wt    = (unsigned short*)d_ws;       // 4 x 1M elems (Wq,Wk,Wv,Wo transposed)
  unsigned short* xbf   = wt + 4 * 1048576;            // 4M elems
  unsigned short* q_ws  = xbf + 4194304;               // Q,K,V contiguous (4M each)
  unsigned short* k_ws  = q_ws + 4194304;
  unsigned short* v_ws  = k_ws + 4194304;
  unsigned short* vt_ws = v_ws + 4194304;
  unsigned short* o_ws  = vt_ws + 4194304;
  float* biasF = (float*)(o_ws + 4194304);             // 16 x 4096 fp32 (log2e-scaled)

  prep_kernel<<<3073, 256, 0, stream>>>(X, Wq, Wk, Wv, Wo, tbl, xbf, wt, biasF);
  gemm_kernel<<<dim3(32, 8, 3), 256, 0, stream>>>(xbf, wt, q_ws, nullptr, 0);
  transpose_b2b<<<dim3(32, 1, 32), 256, 0, stream>>>(v_ws, vt_ws, 64, 2048, 131072L, 131072L);
  attn_kernel<<<dim3(16, 32), 256, 0, stream>>>(q_ws, k_ws, vt_ws, biasF, o_ws);
  gemm_kernel<<<dim3(32, 8, 1), 256, 0, stream>>>(o_ws, wt + 3 * 1048576, nullptr, (float*)d_out, 1);
}